// Round 6
// baseline (292.417 us; speedup 1.0000x reference)
//
#include <hip/hip_runtime.h>

// OctVolSynth: element-wise over 256^3 volume.
//   scaling = lut[label]; v = scaling*texture; v = (v==0) ? 1 : v;
//   out0 = parenchyma * v;  out1 = (label != 0) ? 1.0f : 0.0f
//
// Session: R1-R9 (16B/lane vectorized, asm MLP, nt, persistent pipeline) all
// 99us +/-4%. R10 (BabelStream shape: scalar 4B/lane, 1 elem/thread, 1024-thr
// blocks, no asm) = 88-91us, -10% -- FIRST structural win; access width is a
// real axis; G13 "always vectorize" falsified for this 3R+2W lockstep mix.
// Still 3.75 TB/s combined vs 6.3 copy anchor, pipes idle, occupancy capped
// at ~69% in every short-block round.
//
// R11, single variable vs R10: persistence. 2048 blocks x 1024 thr = exactly
// 2 blocks/CU resident entire kernel (zero block churn, no per-generation
// store-drain/teardown/redispatch bubbles). Each thread: 8 elements at
// grid-span stride; per-sweep DRAM pattern identical to R10. Scalar 4B
// accesses, compiler-scheduled, no asm.
// Predict: churn-real -> 75-82us, occupancy 85-100; null -> +/-3% and the
// remaining suspect is DRAM 3R+2W mix efficiency.

#define N_ELEMS (256 * 256 * 256)
#define LUT_SIZE 302
#define BLOCK 1024
#define GRID 2048
#define SPAN (GRID * BLOCK)          // 2,097,152 elems per sweep
#define ITERS (N_ELEMS / SPAN)       // 8, exact, no tail

__global__ __launch_bounds__(BLOCK) void octvolsynth_r11(
    const int* __restrict__ labels,
    const float* __restrict__ parenchyma,
    const float* __restrict__ texture,
    const float* __restrict__ lut,
    float* __restrict__ out)
{
    __shared__ float s_lut[LUT_SIZE];
    for (int i = threadIdx.x; i < LUT_SIZE; i += BLOCK) s_lut[i] = lut[i];
    __syncthreads();

    const int base = blockIdx.x * BLOCK + threadIdx.x;
    float* __restrict__ outm = out + N_ELEMS;

#pragma unroll
    for (int k = 0; k < ITERS; ++k) {
        const int i = base + k * SPAN;

        const int   l = labels[i];
        const float p = parenchyma[i];
        const float x = texture[i];

        float v = s_lut[l] * x;
        v = (v == 0.0f) ? 1.0f : v;

        out[i]  = p * v;
        outm[i] = (l != 0) ? 1.0f : 0.0f;
    }
}

extern "C" void kernel_launch(void* const* d_in, const int* in_sizes, int n_in,
                              void* d_out, int out_size, void* d_ws, size_t ws_size,
                              hipStream_t stream) {
    const int*   labels     = (const int*)d_in[0];
    const float* parenchyma = (const float*)d_in[1];
    const float* texture    = (const float*)d_in[2];
    const float* lut        = (const float*)d_in[3];
    float* out = (float*)d_out;

    octvolsynth_r11<<<GRID, BLOCK, 0, stream>>>(labels, parenchyma, texture, lut, out);
}

// Round 7
// 277.128 us; speedup vs baseline: 1.0552x; 1.0552x over previous
//
#include <hip/hip_runtime.h>

// OctVolSynth: element-wise over 256^3 volume.
//   scaling = lut[label]; v = scaling*texture; v = (v==0) ? 1 : v;
//   out0 = parenchyma * v;  out1 = (label != 0) ? 1.0f : 0.0f
//
// Session: R1-R9 (16B/lane; incl. forced 6-deep MLP R7, persistent pipeline
// R9) all ~99us / 3.24 TB/s combined -- 16B lockstep bursts cap the 5-stream
// mix regardless of depth. R10 scalar 4B/lane = 88-91us / 3.75 TB/s (win).
// R11 persistent grid-stride regressed (churn axis dead). Unified theory:
// granularity AND in-flight depth are両 defects; R10 fixed granularity but
// holds only ~16KB/CU in flight (Little's-law knee at ~900ns loaded latency).
// R12 = R10 shape + 12 asm-pinned scalar loads in flight per wave (4 elems/
// thread), progressive counted-vmcnt consume (ladder 9/8/7/6, oldest-first
// with stores counted), sched_barrier(0) after each wait (rule #18).
// ~64-96KB/CU in flight at unchanged 256B burst granularity.

#define N_ELEMS (256 * 256 * 256)
#define LUT_SIZE 302
#define BLOCK 1024
#define CHUNKS 4    // elements per thread

typedef float vfloat4 __attribute__((ext_vector_type(4)));

#define GLOADF(dst, off, base)                                        \
  asm volatile("global_load_dword %0, %1, %2"                         \
               : "=&v"(dst) : "v"(off), "s"(base))
#define GLOADI(dst, off, base)                                        \
  asm volatile("global_load_dword %0, %1, %2"                         \
               : "=&v"(dst) : "v"(off), "s"(base))

#define GSTOREF(src, off, base)                                       \
  asm volatile("global_store_dword %0, %1, %2"                        \
               :: "v"(off), "v"(src), "s"(base) : "memory")

#define WAITSB(n)                                                     \
  do { asm volatile("s_waitcnt vmcnt(" #n ")" ::: "memory");          \
       __builtin_amdgcn_sched_barrier(0); } while (0)

__global__ __launch_bounds__(BLOCK) void octvolsynth_r12(
    const int* __restrict__ labels,
    const float* __restrict__ parenchyma,
    const float* __restrict__ texture,
    const float* __restrict__ lut,
    float* __restrict__ out)
{
    __shared__ float s_lut[LUT_SIZE];
    for (int i = threadIdx.x; i < LUT_SIZE; i += BLOCK) s_lut[i] = lut[i];
    __syncthreads();   // drains vmcnt -> manual counting starts at 0

    // byte offsets: element k of this thread at o0 + k*4096
    const unsigned o0 = blockIdx.x * (BLOCK * CHUNKS * 4u) + threadIdx.x * 4u;
    const unsigned o1 = o0 + 1 * BLOCK * 4u;
    const unsigned o2 = o0 + 2 * BLOCK * 4u;
    const unsigned o3 = o0 + 3 * BLOCK * 4u;

    const float* outm = out + N_ELEMS;   // mask plane base

    // ---- issue phase: 12 independent scalar loads, all in flight ----
    int   l0, l1, l2, l3;
    float p0, p1, p2, p3, x0, x1, x2, x3;
    GLOADI(l0, o0, labels); GLOADF(p0, o0, parenchyma); GLOADF(x0, o0, texture);
    GLOADI(l1, o1, labels); GLOADF(p1, o1, parenchyma); GLOADF(x1, o1, texture);
    GLOADI(l2, o2, labels); GLOADF(p2, o2, parenchyma); GLOADF(x2, o2, texture);
    GLOADI(l3, o3, labels); GLOADF(p3, o3, parenchyma); GLOADF(x3, o3, texture);

#define CONSUME(L, P, X, off) do {                                    \
    float v = s_lut[(L)] * (X);                                       \
    v = (v == 0.0f) ? 1.0f : v;                                       \
    float fv = (P) * v;                                               \
    float mv = ((L) != 0) ? 1.0f : 0.0f;                              \
    GSTOREF(fv, (off), out);                                          \
    GSTOREF(mv, (off), outm);                                         \
} while (0)

    // vmcnt ladder, oldest-first retire, stores counted:
    // 12 out -> w(9): l0,p0,x0 done. consume e0 (+2 st, 11 out)
    // w(8): l1,p1,x1 done (8 out). consume e1 (+2, 10)
    // w(7): l2,p2,x2 done (7 out). consume e2 (+2, 9)
    // w(6): l3,p3,x3 done (6 out = 6 stores). consume e3; drain at endpgm
    WAITSB(9);  CONSUME(l0, p0, x0, o0);
    WAITSB(8);  CONSUME(l1, p1, x1, o1);
    WAITSB(7);  CONSUME(l2, p2, x2, o2);
    WAITSB(6);  CONSUME(l3, p3, x3, o3);

#undef CONSUME
}

extern "C" void kernel_launch(void* const* d_in, const int* in_sizes, int n_in,
                              void* d_out, int out_size, void* d_ws, size_t ws_size,
                              hipStream_t stream) {
    const int*   labels     = (const int*)d_in[0];
    const float* parenchyma = (const float*)d_in[1];
    const float* texture    = (const float*)d_in[2];
    const float* lut        = (const float*)d_in[3];
    float* out = (float*)d_out;

    const int grid = N_ELEMS / (BLOCK * CHUNKS);   // 4096 blocks, no tail
    octvolsynth_r12<<<grid, BLOCK, 0, stream>>>(labels, parenchyma, texture, lut, out);
}

// Round 8
// 268.556 us; speedup vs baseline: 1.0889x; 1.0319x over previous
//
#include <hip/hip_runtime.h>

// OctVolSynth: element-wise over 256^3 volume.
//   scaling = lut[label]; v = scaling*texture; v = (v==0) ? 1 : v;
//   out0 = parenchyma * v;  out1 = (label != 0) ? 1.0f : 0.0f
//
// Session: 16B/lane shapes (R1-R9, incl. forced MLP + persistent pipelines)
// all ~99us. R10 scalar 4B/lane compiler-scheduled = 88-91us (base). R11
// persistence regressed; R12 asm-forced 12-deep scalar MLP regressed (99-102,
// occupancy 56%) -- Little's-law depth theory dead; forced-asm scheduling has
// lost/tied in R7/R8/R9/R12. Duration tracks occupancy inversely all session.
//
// Last standing counter-falsifiable theory: L3 write-displacement. Steady
// FETCH=96MiB in a read-once kernel means half the 192MiB input set is L3-
// resident across harness iterations; the 128MiB of output writes allocating
// in the MALL displace the other half (320MiB > 256MiB). R8 proved `nt`
// (eviction hint) moves nothing; R13 tests the STRONG form: system-scope
// stores (sc0 sc1 = SC[1:0]=11 on gfx940+) + nt -> write past the MALL, no
// allocation. Single variable vs R10: store cache policy only; loads remain
// compiler-scheduled (the winning config).
// Predict: bypass-works -> FETCH <20MiB, dur 60-75us; serializes -> >100us;
// unchanged -> cache axis dead, declare mix ceiling after final width probe.

#define N_ELEMS (256 * 256 * 256)
#define LUT_SIZE 302
#define BLOCK 1024

// system-scope non-temporal store: bypass/no-allocate at L2+MALL
#define GSTORE_SYS(val, off, base)                                    \
  asm volatile("global_store_dword %0, %1, %2 sc0 sc1 nt"             \
               :: "v"(off), "v"(val), "s"(base) : "memory")

__global__ __launch_bounds__(BLOCK) void octvolsynth_r13(
    const int* __restrict__ labels,
    const float* __restrict__ parenchyma,
    const float* __restrict__ texture,
    const float* __restrict__ lut,
    float* __restrict__ out)
{
    __shared__ float s_lut[LUT_SIZE];
    for (int i = threadIdx.x; i < LUT_SIZE; i += BLOCK) s_lut[i] = lut[i];
    __syncthreads();

    const int i = blockIdx.x * BLOCK + threadIdx.x;   // one element per thread

    const int   l = labels[i];
    const float p = parenchyma[i];
    const float x = texture[i];

    float v = s_lut[l] * x;
    v = (v == 0.0f) ? 1.0f : v;

    const float fv = p * v;
    const float mv = (l != 0) ? 1.0f : 0.0f;

    const unsigned off = (unsigned)i * 4u;            // byte offset in plane
    const float* outm = out + N_ELEMS;
    GSTORE_SYS(fv, off, out);
    GSTORE_SYS(mv, off, outm);
}

extern "C" void kernel_launch(void* const* d_in, const int* in_sizes, int n_in,
                              void* d_out, int out_size, void* d_ws, size_t ws_size,
                              hipStream_t stream) {
    const int*   labels     = (const int*)d_in[0];
    const float* parenchyma = (const float*)d_in[1];
    const float* texture    = (const float*)d_in[2];
    const float* lut        = (const float*)d_in[3];
    float* out = (float*)d_out;

    const int grid = N_ELEMS / BLOCK;   // 16384 blocks, no tail
    octvolsynth_r13<<<grid, BLOCK, 0, stream>>>(labels, parenchyma, texture, lut, out);
}